// Round 2
// baseline (362.213 us; speedup 1.0000x reference)
//
#include <hip/hip_runtime.h>

#define CH    200
#define NE    8
#define OUTC  (CH - NE + 1)   // 193
#define HW    (128 * 128)     // 16384
#define VEC   4
#define THREADS 256
#define NCHUNKS 8             // 2048 blocks -> 8 blocks/CU, 32 waves/CU

// Each thread: one float4 spatial position, slides an 8-wide channel window.
// x read ~1.25x (chunk overlap), out written exactly once. Memory-bound.
// 2-deep channel prefetch ring (p0,p1) keeps 2 loads in flight per wave.
__device__ __forceinline__ void fma4(float4& a, float s, const float4& v) {
  a.x += s * v.x; a.y += s * v.y; a.z += s * v.z; a.w += s * v.w;
}

__global__ __launch_bounds__(THREADS, 8) void neigh_conv_kernel(
    const float* __restrict__ x, const float* __restrict__ W,
    const float* __restrict__ b, float* __restrict__ out) {
  __shared__ __align__(16) float sW[OUTC * NE];
  __shared__ float sb[OUTC];
  for (int i = threadIdx.x; i < OUTC * NE; i += THREADS) sW[i] = W[i];
  for (int i = threadIdx.x; i < OUTC; i += THREADS) sb[i] = b[i];
  __syncthreads();

  const int pos   = (blockIdx.x * THREADS + threadIdx.x) * VEC;
  const int n     = blockIdx.y;
  const int chunk = blockIdx.z;
  const int c0 = (chunk * OUTC) / NCHUNKS;
  const int c1 = ((chunk + 1) * OUTC) / NCHUNKS;

  const float* xp = x + (size_t)n * CH * HW + pos;
  float* op       = out + (size_t)n * OUTC * HW + pos;

  // Window: win[k] = channel c+k (k=0..6); p0 = channel c+7 (ready),
  // p1 = channel c+8 (in flight). 2 iterations of load slack.
  float4 win[NE - 1];
#pragma unroll
  for (int k = 0; k < NE - 1; ++k)
    win[k] = *(const float4*)(xp + (size_t)(c0 + k) * HW);
  float4 p0 = *(const float4*)(xp + (size_t)(c0 + NE - 1) * HW);
  float4 p1 = *(const float4*)(xp + (size_t)min(c0 + NE, CH - 1) * HW);

  for (int c = c0; c < c1; ++c) {
    const float4 cur = p0;            // channel c+7
    p0 = p1;                          // channel c+8
    // Issue load for channel c+9 (clamped in-bounds; tail loads are
    // redundant-but-safe re-reads of channel 199).
    const int cnext = min(c + NE + 1, CH - 1);
    p1 = *(const float4*)(xp + (size_t)cnext * HW);

    // Weights for out-channel c: two 16B broadcast LDS reads (uniform addr,
    // no bank conflicts) instead of 8 scalar ds_read_b32.
    const float4 w0 = *(const float4*)&sW[c * NE];
    const float4 w1 = *(const float4*)&sW[c * NE + 4];
    const float bb  = sb[c];
    float4 acc = make_float4(bb, bb, bb, bb);
    fma4(acc, w0.x, win[0]);
    fma4(acc, w0.y, win[1]);
    fma4(acc, w0.z, win[2]);
    fma4(acc, w0.w, win[3]);
    fma4(acc, w1.x, win[4]);
    fma4(acc, w1.y, win[5]);
    fma4(acc, w1.z, win[6]);
    fma4(acc, w1.w, cur);
    *(float4*)(op + (size_t)c * HW) = acc;

#pragma unroll
    for (int k = 0; k < NE - 2; ++k) win[k] = win[k + 1];
    win[NE - 2] = cur;
  }
}

extern "C" void kernel_launch(void* const* d_in, const int* in_sizes, int n_in,
                              void* d_out, int out_size, void* d_ws, size_t ws_size,
                              hipStream_t stream) {
  const float* x = (const float*)d_in[0];
  const float* W = (const float*)d_in[1];
  const float* b = (const float*)d_in[2];
  float* out = (float*)d_out;

  // Problem shape is fixed by the reference: x = (16, 200, 128, 128) f32.
  // Deriving N from in_sizes[0] is convention-dependent (elements vs BYTES);
  // if in_sizes were bytes, in_sizes[0]/(CH*HW) = 64 would silently
  // over-launch a 4x grid (first 16 batches still verify). Hard-code N=16.
  const int N = 16;

  dim3 grid(HW / VEC / THREADS /*16*/, N, NCHUNKS);
  neigh_conv_kernel<<<grid, THREADS, 0, stream>>>(x, W, b, out);
}

// Round 4
// 361.690 us; speedup vs baseline: 1.0014x; 1.0014x over previous
//
#include <hip/hip_runtime.h>

#define CH    200
#define NE    8
#define OUTC  (CH - NE + 1)   // 193
#define HW    (128 * 128)     // 16384
#define VEC   4
#define THREADS 256
#define NCHUNKS 4             // 1024 blocks -> 4 blocks/CU, 16 waves/CU
                              // x re-read factor (193+7*4)/200 = 1.105x

// Each thread: one float4 spatial position, slides an 8-wide channel window.
// x read ~1.1x (chunk overlap), out written exactly once. Memory-bound.
// 2-deep channel prefetch ring (p0,p1) keeps 2 loads in flight per wave.
// Non-temporal stores: out has zero reuse; keep L2/L3 for x (210 MB fits L3,
// so the chunk-overlap re-reads can hit Infinity Cache).

// Native clang vector type: __builtin_nontemporal_store requires a scalar or
// native vector pointer (HIP_vector_type<float,4> is a struct -> rejected).
typedef float f32x4 __attribute__((ext_vector_type(4)));

__device__ __forceinline__ void fma4(float4& a, float s, const float4& v) {
  a.x += s * v.x; a.y += s * v.y; a.z += s * v.z; a.w += s * v.w;
}

__global__ __launch_bounds__(THREADS, 4) void neigh_conv_kernel(
    const float* __restrict__ x, const float* __restrict__ W,
    const float* __restrict__ b, float* __restrict__ out) {
  __shared__ __align__(16) float sW[OUTC * NE];
  __shared__ float sb[OUTC];
  for (int i = threadIdx.x; i < OUTC * NE; i += THREADS) sW[i] = W[i];
  for (int i = threadIdx.x; i < OUTC; i += THREADS) sb[i] = b[i];
  __syncthreads();

  const int pos   = (blockIdx.x * THREADS + threadIdx.x) * VEC;
  const int n     = blockIdx.y;
  const int chunk = blockIdx.z;
  const int c0 = (chunk * OUTC) / NCHUNKS;
  const int c1 = ((chunk + 1) * OUTC) / NCHUNKS;

  const float* xp = x + (size_t)n * CH * HW + pos;
  float* op       = out + (size_t)n * OUTC * HW + pos;

  // Window: win[k] = channel c+k (k=0..6); p0 = channel c+7 (ready),
  // p1 = channel c+8 (in flight). 2 iterations of load slack.
  float4 win[NE - 1];
#pragma unroll
  for (int k = 0; k < NE - 1; ++k)
    win[k] = *(const float4*)(xp + (size_t)(c0 + k) * HW);
  float4 p0 = *(const float4*)(xp + (size_t)(c0 + NE - 1) * HW);
  float4 p1 = *(const float4*)(xp + (size_t)min(c0 + NE, CH - 1) * HW);

  for (int c = c0; c < c1; ++c) {
    const float4 cur = p0;            // channel c+7
    p0 = p1;                          // channel c+8
    // Issue load for channel c+9 (clamped in-bounds; tail loads are
    // redundant-but-safe re-reads of channel 199).
    const int cnext = min(c + NE + 1, CH - 1);
    p1 = *(const float4*)(xp + (size_t)cnext * HW);

    // Weights for out-channel c: two 16B broadcast LDS reads (uniform addr,
    // no bank conflicts) instead of 8 scalar ds_read_b32.
    const float4 w0 = *(const float4*)&sW[c * NE];
    const float4 w1 = *(const float4*)&sW[c * NE + 4];
    const float bb  = sb[c];
    float4 acc = make_float4(bb, bb, bb, bb);
    fma4(acc, w0.x, win[0]);
    fma4(acc, w0.y, win[1]);
    fma4(acc, w0.z, win[2]);
    fma4(acc, w0.w, win[3]);
    fma4(acc, w1.x, win[4]);
    fma4(acc, w1.y, win[5]);
    fma4(acc, w1.z, win[6]);
    fma4(acc, w1.w, cur);
    // Non-temporal: out is write-once, never re-read by this kernel.
    f32x4 accv;
    accv.x = acc.x; accv.y = acc.y; accv.z = acc.z; accv.w = acc.w;
    __builtin_nontemporal_store(accv, (f32x4*)(op + (size_t)c * HW));

#pragma unroll
    for (int k = 0; k < NE - 2; ++k) win[k] = win[k + 1];
    win[NE - 2] = cur;
  }
}

extern "C" void kernel_launch(void* const* d_in, const int* in_sizes, int n_in,
                              void* d_out, int out_size, void* d_ws, size_t ws_size,
                              hipStream_t stream) {
  const float* x = (const float*)d_in[0];
  const float* W = (const float*)d_in[1];
  const float* b = (const float*)d_in[2];
  float* out = (float*)d_out;

  // Fixed problem shape: x = (16, 200, 128, 128) f32. N hard-coded (round-1
  // evidence: dur_us identical with hard-coded 16, so no over-launch existed).
  const int N = 16;

  dim3 grid(HW / VEC / THREADS /*16*/, N, NCHUNKS);
  neigh_conv_kernel<<<grid, THREADS, 0, stream>>>(x, W, b, out);
}

// Round 5
// 351.685 us; speedup vs baseline: 1.0299x; 1.0284x over previous
//
#include <hip/hip_runtime.h>

#define CH    200
#define NE    8
#define OUTC  (CH - NE + 1)   // 193
#define HW    (128 * 128)     // 16384
#define VEC   4
#define THREADS 256
#define NCHUNKS 4             // chunks of {48,48,48,49} out-channels
#define NGROUPS 6             // 8-output groups per chunk (48/8); 49th is tail

// 3-bank register pipeline. Banks A,B hold 16 resident input channels;
// C's 8 loads are issued a full group (8 outputs, 64 FMAs) before first use
// (the bank rotation), so each wave keeps ~8 KB of loads in flight.
// All array indices are compile-time (rule #20: no runtime-indexed vectors).
// Round-4 evidence: rotating-window version was demoted to 32 VGPRs
// (window spilled), latency-serialized at 2.4 TB/s, VALUBusy 10%.

typedef float f32x4 __attribute__((ext_vector_type(4)));

__device__ __forceinline__ void fma4(f32x4& a, float s, f32x4 v) {
  a[0] += s * v[0]; a[1] += s * v[1]; a[2] += s * v[2]; a[3] += s * v[3];
}

__global__ __launch_bounds__(THREADS) void neigh_conv_kernel(
    const float* __restrict__ x, const float* __restrict__ W,
    const float* __restrict__ b, float* __restrict__ out) {
  __shared__ __align__(16) float sW[OUTC * NE];
  __shared__ float sb[OUTC];
  for (int i = threadIdx.x; i < OUTC * NE; i += THREADS) sW[i] = W[i];
  for (int i = threadIdx.x; i < OUTC; i += THREADS) sb[i] = b[i];
  __syncthreads();

  const int pos   = (blockIdx.x * THREADS + threadIdx.x) * VEC;
  const int n     = blockIdx.y;
  const int chunk = blockIdx.z;
  const int c0 = (chunk * OUTC) / NCHUNKS;        // 0,48,96,144
  const int c1 = ((chunk + 1) * OUTC) / NCHUNKS;  // 48,96,144,193

  const float* xp = x + (size_t)n * CH * HW + pos;
  float* op       = out + (size_t)n * OUTC * HW + pos;

  f32x4 A[8], B[8], C[8];
  // Prologue: A = channels c0..c0+7, B = c0+8..c0+15 (16 loads in flight).
#pragma unroll
  for (int k = 0; k < 8; ++k)
    A[k] = *(const f32x4*)(xp + (size_t)(c0 + k) * HW);
#pragma unroll
  for (int k = 0; k < 8; ++k)
    B[k] = *(const f32x4*)(xp + (size_t)(c0 + 8 + k) * HW);

  int c = c0;
#pragma unroll 1   // keep 3 physical banks; full unroll would hoist 48 loads
  for (int g = 0; g < NGROUPS; ++g, c += 8) {
    // Issue next bank (channels c+16..c+23, clamped in-bounds; the clamped
    // tail loads are redundant-but-safe re-reads of channel 199).
#pragma unroll
    for (int k = 0; k < 8; ++k) {
      const int ch = min(c + 16 + k, CH - 1);
      C[k] = *(const f32x4*)(xp + (size_t)ch * HW);
    }
    // 8 outputs; output c+j consumes A[j..7] then B[0..j-1].
#pragma unroll
    for (int j = 0; j < 8; ++j) {
      const int cc = c + j;
      const f32x4 w0 = *(const f32x4*)&sW[cc * NE];
      const f32x4 w1 = *(const f32x4*)&sW[cc * NE + 4];
      const float bb = sb[cc];
      f32x4 acc = {bb, bb, bb, bb};
#pragma unroll
      for (int k = 0; k < 8; ++k) {
        const int idx = j + k;                    // compile-time, 0..14
        const f32x4 v = (idx < 8) ? A[idx & 7] : B[idx & 7];
        const float w = (k < 4) ? w0[k] : w1[k - 4];
        fma4(acc, w, v);
      }
      // out is write-once: non-temporal, keep L2/L3 for x.
      __builtin_nontemporal_store(acc, (f32x4*)(op + (size_t)cc * HW));
    }
    // Rotate banks. First use of C => vmcnt wait lands here, a full
    // group's compute after the loads were issued.
#pragma unroll
    for (int k = 0; k < 8; ++k) A[k] = B[k];
#pragma unroll
    for (int k = 0; k < 8; ++k) B[k] = C[k];
  }

  // Tail (only chunk 3: output 192 needs channels 192..199 = current A).
  if (c < c1) {
    const f32x4 w0 = *(const f32x4*)&sW[c * NE];
    const f32x4 w1 = *(const f32x4*)&sW[c * NE + 4];
    const float bb = sb[c];
    f32x4 acc = {bb, bb, bb, bb};
#pragma unroll
    for (int k = 0; k < 8; ++k) {
      const float w = (k < 4) ? w0[k] : w1[k - 4];
      fma4(acc, w, A[k]);
    }
    __builtin_nontemporal_store(acc, (f32x4*)(op + (size_t)c * HW));
  }
}

extern "C" void kernel_launch(void* const* d_in, const int* in_sizes, int n_in,
                              void* d_out, int out_size, void* d_ws, size_t ws_size,
                              hipStream_t stream) {
  const float* x = (const float*)d_in[0];
  const float* W = (const float*)d_in[1];
  const float* b = (const float*)d_in[2];
  float* out = (float*)d_out;

  // Fixed problem shape: x = (16, 200, 128, 128) f32.
  const int N = 16;

  dim3 grid(HW / VEC / THREADS /*16*/, N, NCHUNKS);
  neigh_conv_kernel<<<grid, THREADS, 0, stream>>>(x, W, b, out);
}